// Round 6
// baseline (736.105 us; speedup 1.0000x reference)
//
#include <hip/hip_runtime.h>
#include <hip/hip_bf16.h>
#include <math.h>

// Problem constants
#define BATCH 32
#define IN_LEN 28
#define NN 2048
#define E 256
#define H 512
#define N_LAYERS 3
#define OUT_LEN 28
#define M_ROWS (BATCH * NN)   // 65536

typedef unsigned short u16;
typedef unsigned int   u32;
typedef __attribute__((ext_vector_type(8))) short short8;   // 8 f16 (4 VGPRs)
typedef __attribute__((ext_vector_type(4))) float f32x4;    // MFMA accumulator

// Counted-vmcnt pipeline primitives. Raw barrier (builtin, no compiler
// vmcnt(0) drain) + per-wave counted waits keep prefetch loads in flight
// across barriers.
#define WAITV(N)  asm volatile("s_waitcnt vmcnt(" #N ")" ::: "memory")
#define BARRIER() __builtin_amdgcn_s_barrier()

// T1: XCD-aware bijective block swizzle (m204 form, valid for any nwg).
// Gives each XCD a contiguous chunk of tile space -> A-panels/W-slices are
// fetched into ONE L2 instead of 8.
__device__ __forceinline__ int xcd_swizzle(int orig, int nwg) {
    int xcd = orig & 7;
    int q = nwg >> 3, r8 = nwg & 7;
    int base = (xcd < r8) ? xcd * (q + 1) : r8 * (q + 1) + (xcd - r8) * q;
    return base + (orig >> 3);
}

// ---- fp16 split helpers (RNE casts) ----------------------------------------
__device__ __forceinline__ u16 f2h(float x) {
    union { _Float16 h; u16 u; } v; v.h = (_Float16)x; return v.u;
}
__device__ __forceinline__ float h2f(u16 u) {
    union { _Float16 h; u16 u; } v; v.u = u; return (float)v.h;
}

// async global -> LDS, 16 B per lane. LDS dest = wave-uniform base + lane*16.
__device__ __forceinline__ void gload_lds16(const void* g, void* l) {
    __builtin_amdgcn_global_load_lds(
        (const __attribute__((address_space(1))) void*)g,
        (__attribute__((address_space(3))) void*)l, 16, 0, 0);
}

// ---------------------------------------------------------------------------
// Split BOTH weight tensors into fp16 hi/lo (one launch).
// ---------------------------------------------------------------------------
__global__ __launch_bounds__(256)
void k_split2(const float* __restrict__ w1, const float* __restrict__ w2,
              u16* __restrict__ hi, u16* __restrict__ lo, int nW)
{
    int i = blockIdx.x * 256 + threadIdx.x;
    float v = (i < nW) ? w1[i] : w2[i - nW];
    u16 h = f2h(v);
    hi[i] = h;
    lo[i] = f2h(v - h2f(h));
}

// ---------------------------------------------------------------------------
// Kernel 1: ts = flat @ W_ts^T + b_ts ; h = concat([ts, node_emb]) -> split
// ---------------------------------------------------------------------------
__global__ __launch_bounds__(256)
void k_ts(const float* __restrict__ x_node, const float* __restrict__ node_emb,
          const float* __restrict__ W_ts, const float* __restrict__ b_ts,
          u16* __restrict__ hhi, u16* __restrict__ hlo)
{
    __shared__ float xs[IN_LEN][64];
    const int tid = threadIdx.x;
    const int b   = blockIdx.y;
    const int n0  = blockIdx.x * 64;
    const int c   = tid & 127;        // col pair index
    const int sec = tid >> 7;         // 0: ts, 1: emb (wave-uniform)

    for (int idx = tid; idx < IN_LEN * 64; idx += 256) {
        int l = idx >> 6, i = idx & 63;
        xs[l][i] = x_node[((size_t)b * IN_LEN + l) * NN + n0 + i];
    }

    float w0[IN_LEN], w1[IN_LEN];
    float bias0 = 0.f, bias1 = 0.f;
    if (sec == 0) {
        #pragma unroll
        for (int j = 0; j < IN_LEN; j++) {
            w0[j] = W_ts[(2 * c) * IN_LEN + j];
            w1[j] = W_ts[(2 * c + 1) * IN_LEN + j];
        }
        bias0 = b_ts[2 * c];
        bias1 = b_ts[2 * c + 1];
    }
    __syncthreads();

    for (int i = 0; i < 64; i++) {
        size_t row = (size_t)b * NN + n0 + i;
        u32* oh = (u32*)(hhi + row * H);
        u32* ol = (u32*)(hlo + row * H);
        float v0, v1;
        int oc;
        if (sec == 0) {
            v0 = bias0; v1 = bias1;
            #pragma unroll
            for (int j = 0; j < IN_LEN; j++) {
                float x = xs[j][i];
                v0 += x * w0[j];
                v1 += x * w1[j];
            }
            oc = c;
        } else {
            const float2 ev = *(const float2*)&node_emb[(size_t)(n0 + i) * 256 + 2 * c];
            v0 = ev.x; v1 = ev.y;
            oc = 128 + c;
        }
        u16 h0 = f2h(v0), h1 = f2h(v1);
        oh[oc] = (u32)h0 | ((u32)h1 << 16);
        ol[oc] = (u32)f2h(v0 - h2f(h0)) | ((u32)f2h(v1 - h2f(h1)) << 16);
    }
}

// ---------------------------------------------------------------------------
// Kernel 2a: GEMM1  z = relu(h @ W1^T + b1), h split (3-term), z fp16 SINGLE.
// R3-measured structure (102 us): tile 128x128, 4 waves, BK=32.
// A-hi/A-lo (L3/HBM stream) waves: 3 buffers, distance 2, steady vmcnt(8).
// W waves (L2-resident): 2 buffers, distance 1, vmcnt(0). 80 KB -> 2 blk/CU.
// R6: + XCD bijective swizzle on the block decode (T1).
// ---------------------------------------------------------------------------
__global__ __launch_bounds__(256)
void k_gemm1(const u16* __restrict__ Ahi, const u16* __restrict__ Alo,
             const u16* __restrict__ Whi, const u16* __restrict__ Wlo,
             const float* __restrict__ bias, u16* __restrict__ Z)
{
    __shared__ __align__(16) u16 smem[40960];   // 80 KB

    const int tid = threadIdx.x;
    const int ln  = tid & 63;
    const int wv  = tid >> 6;

    const int id   = xcd_swizzle(blockIdx.x, gridDim.x);
    const int c    = (id >> 3) & 3;
    const int r    = (id & 7) | ((id >> 5) << 3);
    const int row0 = r * 128;
    const int col0 = c * 128;

    const int rbase = (wv & 1) * 64;
    const int cbase = (wv >> 1) * 64;

    const int lr = ln >> 2;
    const int lc = ln & 3;

    // LDS layout (u16 idx): Ahi 3 bufs @0, Alo 3 bufs @12288,
    //                       Whi 2 bufs @24576, Wlo 2 bufs @32768
    const u16* sgsrc; int sofs; int tb;
    if      (wv == 0) { sgsrc = Ahi; sofs = 0;     tb = row0; }
    else if (wv == 1) { sgsrc = Alo; sofs = 12288; tb = row0; }
    else if (wv == 2) { sgsrc = Whi; sofs = 24576; tb = col0; }
    else              { sgsrc = Wlo; sofs = 32768; tb = col0; }

    auto stage = [&](int p, int kt) {
        u16* dstbuf = smem + sofs + p * 4096;
        #pragma unroll
        for (int i = 0; i < 8; i++) {
            int row = i * 16 + lr;
            int sc  = lc ^ ((row >> 1) & 3);
            gload_lds16(sgsrc + (size_t)(tb + row) * H + kt + sc * 8,
                        dstbuf + i * 512);
        }
    };

    f32x4 acc[4][4];
    #pragma unroll
    for (int m = 0; m < 4; m++)
        #pragma unroll
        for (int n = 0; n < 4; n++) acc[m][n] = (f32x4)(0.f);

    // Prologue: A-waves stage tiles 0,1 (16 loads in flight); W-waves tile 0.
    stage(0, 0);
    if (wv < 2) stage(1, 32);

    const int wl = ln & 15;

    for (int t = 0; t < 16; t++) {
        // wait for stage(t) only; keep newer prefetch in flight
        if (wv < 2) { if (t < 15) { WAITV(8); } else { WAITV(0); } }
        else        { WAITV(0); }
        BARRIER();
        // issue next prefetch AFTER barrier (prior reader of that buffer done)
        if (wv < 2) { if (t + 2 < 16) stage((t + 2) % 3, (t + 2) * 32); }
        else        { if (t + 1 < 16) stage((t + 1) & 1, (t + 1) * 32); }

        const int pa = t % 3, pw = t & 1;
        const u16* bAh = smem + 0     + pa * 4096;
        const u16* bAl = smem + 12288 + pa * 4096;
        const u16* bWh = smem + 24576 + pw * 4096;
        const u16* bWl = smem + 32768 + pw * 4096;

        short8 ahi[4], alo[4], whi[4], wlo[4];
        #pragma unroll
        for (int m = 0; m < 4; m++) {
            int rr = rbase + m * 16 + wl;
            int cc = ((ln >> 4) ^ ((rr >> 1) & 3)) * 8;
            ahi[m] = *(const short8*)&bAh[rr * 32 + cc];
            alo[m] = *(const short8*)&bAl[rr * 32 + cc];
        }
        #pragma unroll
        for (int n = 0; n < 4; n++) {
            int wr = cbase + n * 16 + wl;
            int cc = ((ln >> 4) ^ ((wr >> 1) & 3)) * 8;
            whi[n] = *(const short8*)&bWh[wr * 32 + cc];
            wlo[n] = *(const short8*)&bWl[wr * 32 + cc];
        }
        #pragma unroll
        for (int m = 0; m < 4; m++)
            #pragma unroll
            for (int n = 0; n < 4; n++) {
                acc[m][n] = __builtin_amdgcn_mfma_f32_16x16x32_f16(ahi[m], whi[n], acc[m][n], 0, 0, 0);
                acc[m][n] = __builtin_amdgcn_mfma_f32_16x16x32_f16(ahi[m], wlo[n], acc[m][n], 0, 0, 0);
                acc[m][n] = __builtin_amdgcn_mfma_f32_16x16x32_f16(alo[m], whi[n], acc[m][n], 0, 0, 0);
            }
    }

    // ---- LDS-bounce epilogue ----
    __syncthreads();                         // staging LDS dead; reuse
    u16* zb = smem + wv * 4096;              // per-wave 64x64 u16 (8 KB)
    float bv[4];
    #pragma unroll
    for (int n = 0; n < 4; n++) bv[n] = bias[col0 + cbase + n * 16 + wl];
    #pragma unroll
    for (int m = 0; m < 4; m++)
        #pragma unroll
        for (int n = 0; n < 4; n++)
            #pragma unroll
            for (int rg = 0; rg < 4; rg++) {
                int row_l = m * 16 + (ln >> 4) * 4 + rg;
                zb[row_l * 64 + n * 16 + wl] =
                    f2h(fmaxf(acc[m][n][rg] + bv[n], 0.f));
            }
    const int cr = ln >> 3;          // 0..7
    const int cc = (ln & 7) * 8;     // u16 col
    #pragma unroll
    for (int p2 = 0; p2 < 8; p2++) {
        int row_l = cr + p2 * 8;
        uint4 v = *(const uint4*)&zb[row_l * 64 + cc];
        *(uint4*)&Z[(size_t)(row0 + rbase + row_l) * H + col0 + cbase + cc] = v;
    }
}

// ---------------------------------------------------------------------------
// Kernel 2b: GEMM2  h += z @ W2^T + b2, z fp16 single (2-term), out split.
// R3-measured structure (~100 us): Z waves 4 bufs dist-3 vmcnt(8); W waves
// 3 bufs dist-2 vmcnt(8); T14 batch epilogue prefetch. 80 KB -> 2 blk/CU.
// R6: + XCD bijective swizzle on the block decode (T1).
// HEAD=1 (last layer): fused b/g head GEMV; skips HHi/HLo stores.
// ---------------------------------------------------------------------------
template <int HEAD>
__global__ __launch_bounds__(256)
void k_gemm2(const u16* __restrict__ Z,
             const u16* __restrict__ Whi, const u16* __restrict__ Wlo,
             const float* __restrict__ bias,
             u16* HHi, u16* HLo,
             const float* __restrict__ Wb, const float* __restrict__ Wg,
             float* __restrict__ bSum, float* __restrict__ gSum)
{
    __shared__ __align__(16) u16 smem[40960];   // 80 KB

    const int tid = threadIdx.x;
    const int ln  = tid & 63;
    const int wv  = tid >> 6;

    const int id   = xcd_swizzle(blockIdx.x, gridDim.x);
    const int c    = (id >> 3) & 3;
    const int r    = (id & 7) | ((id >> 5) << 3);
    const int row0 = r * 128;
    const int col0 = c * 128;

    const int rbase = (wv & 1) * 64;
    const int cbase = (wv >> 1) * 64;

    const int lr = ln >> 2;
    const int lc = ln & 3;

    // LDS layout (u16 idx): Z 4 bufs @0, Whi 3 bufs @16384, Wlo 3 bufs @28672
    const u16* sgsrc; int sofs; int tb; int iofs; int niss;
    const bool zw = (wv == 0) || (wv == 3);
    if      (wv == 0) { sgsrc = Z;   sofs = 0;     tb = row0;      iofs = 0;    niss = 4; }
    else if (wv == 3) { sgsrc = Z;   sofs = 0;     tb = row0 + 64; iofs = 2048; niss = 4; }
    else if (wv == 1) { sgsrc = Whi; sofs = 16384; tb = col0;      iofs = 0;    niss = 8; }
    else              { sgsrc = Wlo; sofs = 28672; tb = col0;      iofs = 0;    niss = 8; }

    auto stage = [&](int p, int kt) {
        u16* dstbuf = smem + sofs + p * 4096 + iofs;
        #pragma unroll
        for (int i = 0; i < 8; i++) {
            if (i >= niss) break;
            int row = i * 16 + lr;
            int sc  = lc ^ ((row >> 1) & 3);
            gload_lds16(sgsrc + (size_t)(tb + row) * H + kt + sc * 8,
                        dstbuf + i * 512);
        }
    };

    f32x4 acc[4][4];
    #pragma unroll
    for (int m = 0; m < 4; m++)
        #pragma unroll
        for (int n = 0; n < 4; n++) acc[m][n] = (f32x4)(0.f);

    // Prologue: Z-waves stage 0,1,2 (12 loads); W-waves stage 0,1 (16 loads).
    stage(0, 0);
    if (zw) { stage(1, 32); stage(2, 64); }
    else    { stage(1, 32); }

    const int wl = ln & 15;

    for (int t = 0; t < 16; t++) {
        if (zw) {
            // outstanding: stage(t..t+2) = 12 -> vmcnt(8) retires stage(t)
            if      (t < 14) { WAITV(8); }
            else if (t == 14){ WAITV(4); }
            else             { WAITV(0); }
        } else {
            // outstanding: stage(t),stage(t+1) = 16 -> vmcnt(8) retires stage(t)
            if (t < 15) { WAITV(8); } else { WAITV(0); }
        }
        BARRIER();
        if (zw) { if (t + 3 < 16) stage((t + 3) & 3, (t + 3) * 32); }
        else    { if (t + 2 < 16) stage((t + 2) % 3, (t + 2) * 32); }

        const int pz = t & 3, pw = t % 3;
        const u16* bZ  = smem + 0     + pz * 4096;
        const u16* bWh = smem + 16384 + pw * 4096;
        const u16* bWl = smem + 28672 + pw * 4096;

        short8 az[4], whi[4], wlo[4];
        #pragma unroll
        for (int m = 0; m < 4; m++) {
            int rr = rbase + m * 16 + wl;
            int cc = ((ln >> 4) ^ ((rr >> 1) & 3)) * 8;
            az[m] = *(const short8*)&bZ[rr * 32 + cc];
        }
        #pragma unroll
        for (int n = 0; n < 4; n++) {
            int wr = cbase + n * 16 + wl;
            int cc = ((ln >> 4) ^ ((wr >> 1) & 3)) * 8;
            whi[n] = *(const short8*)&bWh[wr * 32 + cc];
            wlo[n] = *(const short8*)&bWl[wr * 32 + cc];
        }
        #pragma unroll
        for (int m = 0; m < 4; m++)
            #pragma unroll
            for (int n = 0; n < 4; n++) {
                acc[m][n] = __builtin_amdgcn_mfma_f32_16x16x32_f16(az[m], whi[n], acc[m][n], 0, 0, 0);
                acc[m][n] = __builtin_amdgcn_mfma_f32_16x16x32_f16(az[m], wlo[n], acc[m][n], 0, 0, 0);
            }
    }

    // ---- epilogue: batch-prefetch ALL global reads, then LDS-bounce ----
    const int cr  = ln >> 3;           // 0..7
    const int ccl = (ln & 7) * 4;      // u16 col within 32

    uint2  uhv[2][8], ulv[2][8];
    float4 bvv[2], hbv[2], hgv[2];
    #pragma unroll
    for (int nh = 0; nh < 2; nh++) {
        const int gc0 = col0 + cbase + nh * 32 + ccl;
        bvv[nh] = *(const float4*)&bias[gc0];
        if (HEAD) {
            hbv[nh] = *(const float4*)&Wb[gc0];
            hgv[nh] = *(const float4*)&Wg[gc0];
        }
        #pragma unroll
        for (int p2 = 0; p2 < 8; p2++) {
            size_t gidx = (size_t)(row0 + rbase + cr + p2 * 8) * H + gc0;
            uhv[nh][p2] = *(const uint2*)(HHi + gidx);
            ulv[nh][p2] = *(const uint2*)(HLo + gidx);
        }
    }

    BARRIER();                                    // staging LDS dead; reuse
    float* fb = (float*)smem + wv * 2048;         // per-wave 64x32 f32 (8 KB)

    float pb[8], pg[8];
    if (HEAD) {
        #pragma unroll
        for (int p2 = 0; p2 < 8; p2++) { pb[p2] = 0.f; pg[p2] = 0.f; }
    }

    #pragma unroll
    for (int nh = 0; nh < 2; nh++) {
        #pragma unroll
        for (int m = 0; m < 4; m++)
            #pragma unroll
            for (int j = 0; j < 2; j++)
                #pragma unroll
                for (int rg = 0; rg < 4; rg++) {
                    int row_l = m * 16 + (ln >> 4) * 4 + rg;
                    fb[row_l * 32 + j * 16 + wl] = acc[m][nh * 2 + j][rg];
                }
        const int gc0 = col0 + cbase + nh * 32 + ccl;
        const float4 bv = bvv[nh];
        #pragma unroll
        for (int p2 = 0; p2 < 8; p2++) {
            int row_l = cr + p2 * 8;
            size_t gidx = (size_t)(row0 + rbase + row_l) * H + gc0;
            uint2 uh = uhv[nh][p2];
            uint2 ul = ulv[nh][p2];
            float4 a = *(const float4*)&fb[row_l * 32 + ccl];
            float v0 = a.x + bv.x + h2f((u16)(uh.x & 0xFFFF)) + h2f((u16)(ul.x & 0xFFFF));
            float v1 = a.y + bv.y + h2f((u16)(uh.x >> 16))    + h2f((u16)(ul.x >> 16));
            float v2 = a.z + bv.z + h2f((u16)(uh.y & 0xFFFF)) + h2f((u16)(ul.y & 0xFFFF));
            float v3 = a.w + bv.w + h2f((u16)(uh.y >> 16))    + h2f((u16)(ul.y >> 16));
            if (HEAD) {
                pb[p2] += v0 * hbv[nh].x + v1 * hbv[nh].y + v2 * hbv[nh].z + v3 * hbv[nh].w;
                pg[p2] += v0 * hgv[nh].x + v1 * hgv[nh].y + v2 * hgv[nh].z + v3 * hgv[nh].w;
            } else {
                u16 h0 = f2h(v0), h1 = f2h(v1), h2 = f2h(v2), h3 = f2h(v3);
                uint2 oh, ol;
                oh.x = (u32)h0 | ((u32)h1 << 16);
                oh.y = (u32)h2 | ((u32)h3 << 16);
                ol.x = (u32)f2h(v0 - h2f(h0)) | ((u32)f2h(v1 - h2f(h1)) << 16);
                ol.y = (u32)f2h(v2 - h2f(h2)) | ((u32)f2h(v3 - h2f(h3)) << 16);
                *(uint2*)(HHi + gidx) = oh;
                *(uint2*)(HLo + gidx) = ol;
            }
        }
    }

    if (HEAD) {
        #pragma unroll
        for (int p2 = 0; p2 < 8; p2++) {
            float sb = pb[p2], sg = pg[p2];
            #pragma unroll
            for (int off = 1; off < 8; off <<= 1) {
                sb += __shfl_xor(sb, off);
                sg += __shfl_xor(sg, off);
            }
            if ((ln & 7) == 0) {
                int grow = row0 + rbase + cr + p2 * 8;
                atomicAdd(&bSum[grow], sb);
                atomicAdd(&gSum[grow], sg);
            }
        }
    }
}

// ---------------------------------------------------------------------------
// Kernel 4: per-(b,n) SIR recurrence (applies head sigmoids itself).
// ---------------------------------------------------------------------------
__global__ __launch_bounds__(256)
void k_sir(const float* __restrict__ x_state,
           const float* __restrict__ bSum, const float* __restrict__ gSum,
           const float* __restrict__ bb, const float* __restrict__ bg,
           float* __restrict__ out)
{
    const int row = blockIdx.x * 256 + threadIdx.x;   // b*NN + n
    const int bb_ = row / NN;
    const int n   = row % NN;

    const float g = 1.f / (1.f + expf(-(gSum[row] + bg[0])));
    const float b = 1.f / (1.f + expf(-(bSum[row] + bb[0])));
    const float d = expf(-g);

    const float* xs = x_state + ((size_t)bb_ * IN_LEN) * (NN * 3) + (size_t)n * 3;

    float x1_prev = xs[1];
    float Ih_prev = x1_prev / g;
    float acc = 0.f;
    #pragma unroll 4
    for (int t = 1; t <= IN_LEN - 1; ++t) {
        float x1 = xs[(size_t)t * (NN * 3) + 1];
        float Ih = x1 / g;
        float Iin = fmaxf(Ih - Ih_prev + x1_prev, 0.f);
        acc = acc * d + Iin;
        Ih_prev = Ih;
        x1_prev = x1;
    }
    float ITm1 = acc * d;
    float Npop = xs[(size_t)(IN_LEN - 1) * (NN * 3) + 2];
    float RTm1 = Npop - xs[(size_t)(IN_LEN - 2) * (NN * 3) + 0];
    float STm1 = Npop - ITm1 - RTm1;
    float Iin0 = b * STm1 * ITm1 / Npop;
    float S = STm1 - Iin0;
    float I = d * (ITm1 + Iin0);

    float* op = out + ((size_t)bb_ * OUT_LEN) * NN + n;
    #pragma unroll 4
    for (int k = 0; k < OUT_LEN; k++) {
        float Iin = b * S * I / Npop;
        S = S - Iin;
        float Rin = g * I;
        I = d * (I + Iin);
        op[(size_t)k * NN] = Rin;
    }
}

// ---------------------------------------------------------------------------
extern "C" void kernel_launch(void* const* d_in, const int* in_sizes, int n_in,
                              void* d_out, int out_size, void* d_ws, size_t ws_size,
                              hipStream_t stream)
{
    const float* x_node   = (const float*)d_in[0];
    const float* x_state  = (const float*)d_in[1];
    const float* node_emb = (const float*)d_in[2];
    const float* W_ts     = (const float*)d_in[3];
    const float* b_ts     = (const float*)d_in[4];
    const float* enc_W1   = (const float*)d_in[5];
    const float* enc_b1   = (const float*)d_in[6];
    const float* enc_W2   = (const float*)d_in[7];
    const float* enc_b2   = (const float*)d_in[8];
    const float* Wb       = (const float*)d_in[9];
    const float* bb       = (const float*)d_in[10];
    const float* Wg       = (const float*)d_in[11];
    const float* bg       = (const float*)d_in[12];
    float* out = (float*)d_out;

    // Workspace: hhi 64M | hlo 64M | wHi 3M | wLo 3M | bSum | gSum | z (chunked)
    u16* hhi   = (u16*)d_ws;
    u16* hlo   = hhi + (size_t)M_ROWS * H;
    u16* wHi   = hlo + (size_t)M_ROWS * H;          // [6][512][512]
    u16* wLo   = wHi + (size_t)6 * H * H;
    float* bSum = (float*)(wLo + (size_t)6 * H * H);
    float* gSum = bSum + M_ROWS;
    u16* z     = (u16*)(gSum + M_ROWS);

    size_t used  = (size_t)((char*)z - (char*)d_ws);
    size_t avail = (ws_size > used) ? ws_size - used : 0;
    long long chunkLL = (long long)(avail / (H * sizeof(u16))) & ~1023LL;
    int chunk = (chunkLL > M_ROWS) ? M_ROWS : (int)chunkLL;
    if (chunk < 1024) chunk = 1024;
    // (R11 measured: L3 already absorbs the h/z re-reads; row-chunking through
    // layers added dispatch overhead with no fetch reduction. Full-M it is.)

    // zero the head accumulators (d_ws is re-poisoned before every call)
    hipMemsetAsync(bSum, 0, 2 * (size_t)M_ROWS * sizeof(float), stream);

    // weight conversion (redone every call)
    const int nW = N_LAYERS * H * H;   // 786432
    k_split2<<<2 * nW / 256, 256, 0, stream>>>(enc_W1, enc_W2, wHi, wLo, nW);

    // 1. build h (split)
    k_ts<<<dim3(NN / 64, BATCH), 256, 0, stream>>>(x_node, node_emb, W_ts, b_ts, hhi, hlo);

    // 2. encoder layers
    for (int l = 0; l < N_LAYERS; l++) {
        const u16* W1hi = wHi + (size_t)l * H * H;
        const u16* W1lo = wLo + (size_t)l * H * H;
        const u16* W2hi = wHi + (size_t)nW + (size_t)l * H * H;
        const u16* W2lo = wLo + (size_t)nW + (size_t)l * H * H;
        const float* b1 = enc_b1 + (size_t)l * H;
        const float* b2 = enc_b2 + (size_t)l * H;
        for (int r = 0; r < M_ROWS; r += chunk) {
            int rows = (M_ROWS - r < chunk) ? (M_ROWS - r) : chunk;
            u16* hrhi = hhi + (size_t)r * H;
            u16* hrlo = hlo + (size_t)r * H;
            int nblk = (rows / 128) * 4;
            k_gemm1<<<nblk, 256, 0, stream>>>(hrhi, hrlo, W1hi, W1lo, b1, z);
            if (l < N_LAYERS - 1)
                k_gemm2<0><<<nblk, 256, 0, stream>>>(z, W2hi, W2lo, b2, hrhi, hrlo,
                                                     Wb, Wg, bSum + r, gSum + r);
            else
                k_gemm2<1><<<nblk, 256, 0, stream>>>(z, W2hi, W2lo, b2, hrhi, hrlo,
                                                     Wb, Wg, bSum + r, gSum + r);
        }
    }

    // 3. SIR recurrence + output (head sigmoid fused)
    k_sir<<<M_ROWS / 256, 256, 0, stream>>>(x_state, bSum, gSum, bb, bg, out);
}

// Round 7
// 731.376 us; speedup vs baseline: 1.0065x; 1.0065x over previous
//
#include <hip/hip_runtime.h>
#include <hip/hip_bf16.h>
#include <math.h>

// Problem constants
#define BATCH 32
#define IN_LEN 28
#define NN 2048
#define E 256
#define H 512
#define N_LAYERS 3
#define OUT_LEN 28
#define M_ROWS (BATCH * NN)   // 65536

typedef unsigned short u16;
typedef unsigned int   u32;
typedef __attribute__((ext_vector_type(8))) short short8;   // 8 f16 (4 VGPRs)
typedef __attribute__((ext_vector_type(4))) float f32x4;    // MFMA accumulator

// Counted-vmcnt pipeline primitives. Raw barrier (builtin, no compiler
// vmcnt(0) drain) + per-wave counted waits keep prefetch loads in flight
// across barriers.
#define WAITV(N)  asm volatile("s_waitcnt vmcnt(" #N ")" ::: "memory")
#define BARRIER() __builtin_amdgcn_s_barrier()

// ---- fp16 split helpers (RNE casts) ----------------------------------------
__device__ __forceinline__ u16 f2h(float x) {
    union { _Float16 h; u16 u; } v; v.h = (_Float16)x; return v.u;
}
__device__ __forceinline__ float h2f(u16 u) {
    union { _Float16 h; u16 u; } v; v.u = u; return (float)v.h;
}

// async global -> LDS, 16 B per lane. LDS dest = wave-uniform base + lane*16.
__device__ __forceinline__ void gload_lds16(const void* g, void* l) {
    __builtin_amdgcn_global_load_lds(
        (const __attribute__((address_space(1))) void*)g,
        (__attribute__((address_space(3))) void*)l, 16, 0, 0);
}

// ---------------------------------------------------------------------------
// Split BOTH weight tensors into fp16 hi/lo (one launch).
// ---------------------------------------------------------------------------
__global__ __launch_bounds__(256)
void k_split2(const float* __restrict__ w1, const float* __restrict__ w2,
              u16* __restrict__ hi, u16* __restrict__ lo, int nW)
{
    int i = blockIdx.x * 256 + threadIdx.x;
    float v = (i < nW) ? w1[i] : w2[i - nW];
    u16 h = f2h(v);
    hi[i] = h;
    lo[i] = f2h(v - h2f(h));
}

// ---------------------------------------------------------------------------
// Kernel 1: ts = flat @ W_ts^T + b_ts ; h = concat([ts, node_emb]) -> split
// ---------------------------------------------------------------------------
__global__ __launch_bounds__(256)
void k_ts(const float* __restrict__ x_node, const float* __restrict__ node_emb,
          const float* __restrict__ W_ts, const float* __restrict__ b_ts,
          u16* __restrict__ hhi, u16* __restrict__ hlo)
{
    __shared__ float xs[IN_LEN][64];
    const int tid = threadIdx.x;
    const int b   = blockIdx.y;
    const int n0  = blockIdx.x * 64;
    const int c   = tid & 127;        // col pair index
    const int sec = tid >> 7;         // 0: ts, 1: emb (wave-uniform)

    for (int idx = tid; idx < IN_LEN * 64; idx += 256) {
        int l = idx >> 6, i = idx & 63;
        xs[l][i] = x_node[((size_t)b * IN_LEN + l) * NN + n0 + i];
    }

    float w0[IN_LEN], w1[IN_LEN];
    float bias0 = 0.f, bias1 = 0.f;
    if (sec == 0) {
        #pragma unroll
        for (int j = 0; j < IN_LEN; j++) {
            w0[j] = W_ts[(2 * c) * IN_LEN + j];
            w1[j] = W_ts[(2 * c + 1) * IN_LEN + j];
        }
        bias0 = b_ts[2 * c];
        bias1 = b_ts[2 * c + 1];
    }
    __syncthreads();

    for (int i = 0; i < 64; i++) {
        size_t row = (size_t)b * NN + n0 + i;
        u32* oh = (u32*)(hhi + row * H);
        u32* ol = (u32*)(hlo + row * H);
        float v0, v1;
        int oc;
        if (sec == 0) {
            v0 = bias0; v1 = bias1;
            #pragma unroll
            for (int j = 0; j < IN_LEN; j++) {
                float x = xs[j][i];
                v0 += x * w0[j];
                v1 += x * w1[j];
            }
            oc = c;
        } else {
            const float2 ev = *(const float2*)&node_emb[(size_t)(n0 + i) * 256 + 2 * c];
            v0 = ev.x; v1 = ev.y;
            oc = 128 + c;
        }
        u16 h0 = f2h(v0), h1 = f2h(v1);
        oh[oc] = (u32)h0 | ((u32)h1 << 16);
        ol[oc] = (u32)f2h(v0 - h2f(h0)) | ((u32)f2h(v1 - h2f(h1)) << 16);
    }
}

// ---------------------------------------------------------------------------
// Kernel 2a: GEMM1  z = relu(h @ W1^T + b1), h split (3-term), z fp16 SINGLE.
// R3-measured structure (102 us): tile 128x128, 4 waves, BK=32.
// A-hi/A-lo (L3/HBM stream) waves: 3 buffers, distance 2, steady vmcnt(8).
// W waves (L2-resident): 2 buffers, distance 1, vmcnt(0). 80 KB -> 2 blk/CU.
// (R6 measured: XCD swizzle is net-negative here — L3 already absorbs the
//  working set; removed.)
// ---------------------------------------------------------------------------
__global__ __launch_bounds__(256)
void k_gemm1(const u16* __restrict__ Ahi, const u16* __restrict__ Alo,
             const u16* __restrict__ Whi, const u16* __restrict__ Wlo,
             const float* __restrict__ bias, u16* __restrict__ Z)
{
    __shared__ __align__(16) u16 smem[40960];   // 80 KB

    const int tid = threadIdx.x;
    const int ln  = tid & 63;
    const int wv  = tid >> 6;

    const int id   = blockIdx.x;
    const int c    = (id >> 3) & 3;
    const int r    = (id & 7) | ((id >> 5) << 3);
    const int row0 = r * 128;
    const int col0 = c * 128;

    const int rbase = (wv & 1) * 64;
    const int cbase = (wv >> 1) * 64;

    const int lr = ln >> 2;
    const int lc = ln & 3;

    // LDS layout (u16 idx): Ahi 3 bufs @0, Alo 3 bufs @12288,
    //                       Whi 2 bufs @24576, Wlo 2 bufs @32768
    const u16* sgsrc; int sofs; int tb;
    if      (wv == 0) { sgsrc = Ahi; sofs = 0;     tb = row0; }
    else if (wv == 1) { sgsrc = Alo; sofs = 12288; tb = row0; }
    else if (wv == 2) { sgsrc = Whi; sofs = 24576; tb = col0; }
    else              { sgsrc = Wlo; sofs = 32768; tb = col0; }

    auto stage = [&](int p, int kt) {
        u16* dstbuf = smem + sofs + p * 4096;
        #pragma unroll
        for (int i = 0; i < 8; i++) {
            int row = i * 16 + lr;
            int sc  = lc ^ ((row >> 1) & 3);
            gload_lds16(sgsrc + (size_t)(tb + row) * H + kt + sc * 8,
                        dstbuf + i * 512);
        }
    };

    f32x4 acc[4][4];
    #pragma unroll
    for (int m = 0; m < 4; m++)
        #pragma unroll
        for (int n = 0; n < 4; n++) acc[m][n] = (f32x4)(0.f);

    // Prologue: A-waves stage tiles 0,1 (16 loads in flight); W-waves tile 0.
    stage(0, 0);
    if (wv < 2) stage(1, 32);

    const int wl = ln & 15;

    for (int t = 0; t < 16; t++) {
        // wait for stage(t) only; keep newer prefetch in flight
        if (wv < 2) { if (t < 15) { WAITV(8); } else { WAITV(0); } }
        else        { WAITV(0); }
        BARRIER();
        // issue next prefetch AFTER barrier (prior reader of that buffer done)
        if (wv < 2) { if (t + 2 < 16) stage((t + 2) % 3, (t + 2) * 32); }
        else        { if (t + 1 < 16) stage((t + 1) & 1, (t + 1) * 32); }

        const int pa = t % 3, pw = t & 1;
        const u16* bAh = smem + 0     + pa * 4096;
        const u16* bAl = smem + 12288 + pa * 4096;
        const u16* bWh = smem + 24576 + pw * 4096;
        const u16* bWl = smem + 32768 + pw * 4096;

        short8 ahi[4], alo[4], whi[4], wlo[4];
        #pragma unroll
        for (int m = 0; m < 4; m++) {
            int rr = rbase + m * 16 + wl;
            int cc = ((ln >> 4) ^ ((rr >> 1) & 3)) * 8;
            ahi[m] = *(const short8*)&bAh[rr * 32 + cc];
            alo[m] = *(const short8*)&bAl[rr * 32 + cc];
        }
        #pragma unroll
        for (int n = 0; n < 4; n++) {
            int wr = cbase + n * 16 + wl;
            int cc = ((ln >> 4) ^ ((wr >> 1) & 3)) * 8;
            whi[n] = *(const short8*)&bWh[wr * 32 + cc];
            wlo[n] = *(const short8*)&bWl[wr * 32 + cc];
        }
        #pragma unroll
        for (int m = 0; m < 4; m++)
            #pragma unroll
            for (int n = 0; n < 4; n++) {
                acc[m][n] = __builtin_amdgcn_mfma_f32_16x16x32_f16(ahi[m], whi[n], acc[m][n], 0, 0, 0);
                acc[m][n] = __builtin_amdgcn_mfma_f32_16x16x32_f16(ahi[m], wlo[n], acc[m][n], 0, 0, 0);
                acc[m][n] = __builtin_amdgcn_mfma_f32_16x16x32_f16(alo[m], whi[n], acc[m][n], 0, 0, 0);
            }
    }

    // ---- LDS-bounce epilogue ----
    __syncthreads();                         // staging LDS dead; reuse
    u16* zb = smem + wv * 4096;              // per-wave 64x64 u16 (8 KB)
    float bv[4];
    #pragma unroll
    for (int n = 0; n < 4; n++) bv[n] = bias[col0 + cbase + n * 16 + wl];
    #pragma unroll
    for (int m = 0; m < 4; m++)
        #pragma unroll
        for (int n = 0; n < 4; n++)
            #pragma unroll
            for (int rg = 0; rg < 4; rg++) {
                int row_l = m * 16 + (ln >> 4) * 4 + rg;
                zb[row_l * 64 + n * 16 + wl] =
                    f2h(fmaxf(acc[m][n][rg] + bv[n], 0.f));
            }
    const int cr = ln >> 3;          // 0..7
    const int cc = (ln & 7) * 8;     // u16 col
    #pragma unroll
    for (int p2 = 0; p2 < 8; p2++) {
        int row_l = cr + p2 * 8;
        uint4 v = *(const uint4*)&zb[row_l * 64 + cc];
        *(uint4*)&Z[(size_t)(row0 + rbase + row_l) * H + col0 + cbase + cc] = v;
    }
}

// ---------------------------------------------------------------------------
// Kernel 2b: GEMM2  h += z @ W2^T + b2, z fp16 single (2-term), out split.
// R3-measured structure (~100 us): Z waves 4 bufs dist-3 vmcnt(8); W waves
// 3 bufs dist-2 vmcnt(8); T14 batch epilogue prefetch. 80 KB -> 2 blk/CU.
// HEAD=1 (last layer): fused b/g head GEMV; skips HHi/HLo stores.
// ---------------------------------------------------------------------------
template <int HEAD>
__global__ __launch_bounds__(256)
void k_gemm2(const u16* __restrict__ Z,
             const u16* __restrict__ Whi, const u16* __restrict__ Wlo,
             const float* __restrict__ bias,
             u16* HHi, u16* HLo,
             const float* __restrict__ Wb, const float* __restrict__ Wg,
             float* __restrict__ bSum, float* __restrict__ gSum)
{
    __shared__ __align__(16) u16 smem[40960];   // 80 KB

    const int tid = threadIdx.x;
    const int ln  = tid & 63;
    const int wv  = tid >> 6;

    const int id   = blockIdx.x;
    const int c    = (id >> 3) & 3;
    const int r    = (id & 7) | ((id >> 5) << 3);
    const int row0 = r * 128;
    const int col0 = c * 128;

    const int rbase = (wv & 1) * 64;
    const int cbase = (wv >> 1) * 64;

    const int lr = ln >> 2;
    const int lc = ln & 3;

    // LDS layout (u16 idx): Z 4 bufs @0, Whi 3 bufs @16384, Wlo 3 bufs @28672
    const u16* sgsrc; int sofs; int tb; int iofs; int niss;
    const bool zw = (wv == 0) || (wv == 3);
    if      (wv == 0) { sgsrc = Z;   sofs = 0;     tb = row0;      iofs = 0;    niss = 4; }
    else if (wv == 3) { sgsrc = Z;   sofs = 0;     tb = row0 + 64; iofs = 2048; niss = 4; }
    else if (wv == 1) { sgsrc = Whi; sofs = 16384; tb = col0;      iofs = 0;    niss = 8; }
    else              { sgsrc = Wlo; sofs = 28672; tb = col0;      iofs = 0;    niss = 8; }

    auto stage = [&](int p, int kt) {
        u16* dstbuf = smem + sofs + p * 4096 + iofs;
        #pragma unroll
        for (int i = 0; i < 8; i++) {
            if (i >= niss) break;
            int row = i * 16 + lr;
            int sc  = lc ^ ((row >> 1) & 3);
            gload_lds16(sgsrc + (size_t)(tb + row) * H + kt + sc * 8,
                        dstbuf + i * 512);
        }
    };

    f32x4 acc[4][4];
    #pragma unroll
    for (int m = 0; m < 4; m++)
        #pragma unroll
        for (int n = 0; n < 4; n++) acc[m][n] = (f32x4)(0.f);

    // Prologue: Z-waves stage 0,1,2 (12 loads); W-waves stage 0,1 (16 loads).
    stage(0, 0);
    if (zw) { stage(1, 32); stage(2, 64); }
    else    { stage(1, 32); }

    const int wl = ln & 15;

    for (int t = 0; t < 16; t++) {
        if (zw) {
            // outstanding: stage(t..t+2) = 12 -> vmcnt(8) retires stage(t)
            if      (t < 14) { WAITV(8); }
            else if (t == 14){ WAITV(4); }
            else             { WAITV(0); }
        } else {
            // outstanding: stage(t),stage(t+1) = 16 -> vmcnt(8) retires stage(t)
            if (t < 15) { WAITV(8); } else { WAITV(0); }
        }
        BARRIER();
        if (zw) { if (t + 3 < 16) stage((t + 3) & 3, (t + 3) * 32); }
        else    { if (t + 2 < 16) stage((t + 2) % 3, (t + 2) * 32); }

        const int pz = t & 3, pw = t % 3;
        const u16* bZ  = smem + 0     + pz * 4096;
        const u16* bWh = smem + 16384 + pw * 4096;
        const u16* bWl = smem + 28672 + pw * 4096;

        short8 az[4], whi[4], wlo[4];
        #pragma unroll
        for (int m = 0; m < 4; m++) {
            int rr = rbase + m * 16 + wl;
            int cc = ((ln >> 4) ^ ((rr >> 1) & 3)) * 8;
            az[m] = *(const short8*)&bZ[rr * 32 + cc];
        }
        #pragma unroll
        for (int n = 0; n < 4; n++) {
            int wr = cbase + n * 16 + wl;
            int cc = ((ln >> 4) ^ ((wr >> 1) & 3)) * 8;
            whi[n] = *(const short8*)&bWh[wr * 32 + cc];
            wlo[n] = *(const short8*)&bWl[wr * 32 + cc];
        }
        #pragma unroll
        for (int m = 0; m < 4; m++)
            #pragma unroll
            for (int n = 0; n < 4; n++) {
                acc[m][n] = __builtin_amdgcn_mfma_f32_16x16x32_f16(az[m], whi[n], acc[m][n], 0, 0, 0);
                acc[m][n] = __builtin_amdgcn_mfma_f32_16x16x32_f16(az[m], wlo[n], acc[m][n], 0, 0, 0);
            }
    }

    // ---- epilogue: batch-prefetch ALL global reads, then LDS-bounce ----
    const int cr  = ln >> 3;           // 0..7
    const int ccl = (ln & 7) * 4;      // u16 col within 32

    uint2  uhv[2][8], ulv[2][8];
    float4 bvv[2], hbv[2], hgv[2];
    #pragma unroll
    for (int nh = 0; nh < 2; nh++) {
        const int gc0 = col0 + cbase + nh * 32 + ccl;
        bvv[nh] = *(const float4*)&bias[gc0];
        if (HEAD) {
            hbv[nh] = *(const float4*)&Wb[gc0];
            hgv[nh] = *(const float4*)&Wg[gc0];
        }
        #pragma unroll
        for (int p2 = 0; p2 < 8; p2++) {
            size_t gidx = (size_t)(row0 + rbase + cr + p2 * 8) * H + gc0;
            uhv[nh][p2] = *(const uint2*)(HHi + gidx);
            ulv[nh][p2] = *(const uint2*)(HLo + gidx);
        }
    }

    BARRIER();                                    // staging LDS dead; reuse
    float* fb = (float*)smem + wv * 2048;         // per-wave 64x32 f32 (8 KB)

    float pb[8], pg[8];
    if (HEAD) {
        #pragma unroll
        for (int p2 = 0; p2 < 8; p2++) { pb[p2] = 0.f; pg[p2] = 0.f; }
    }

    #pragma unroll
    for (int nh = 0; nh < 2; nh++) {
        #pragma unroll
        for (int m = 0; m < 4; m++)
            #pragma unroll
            for (int j = 0; j < 2; j++)
                #pragma unroll
                for (int rg = 0; rg < 4; rg++) {
                    int row_l = m * 16 + (ln >> 4) * 4 + rg;
                    fb[row_l * 32 + j * 16 + wl] = acc[m][nh * 2 + j][rg];
                }
        const int gc0 = col0 + cbase + nh * 32 + ccl;
        const float4 bv = bvv[nh];
        #pragma unroll
        for (int p2 = 0; p2 < 8; p2++) {
            int row_l = cr + p2 * 8;
            size_t gidx = (size_t)(row0 + rbase + row_l) * H + gc0;
            uint2 uh = uhv[nh][p2];
            uint2 ul = ulv[nh][p2];
            float4 a = *(const float4*)&fb[row_l * 32 + ccl];
            float v0 = a.x + bv.x + h2f((u16)(uh.x & 0xFFFF)) + h2f((u16)(ul.x & 0xFFFF));
            float v1 = a.y + bv.y + h2f((u16)(uh.x >> 16))    + h2f((u16)(ul.x >> 16));
            float v2 = a.z + bv.z + h2f((u16)(uh.y & 0xFFFF)) + h2f((u16)(ul.y & 0xFFFF));
            float v3 = a.w + bv.w + h2f((u16)(uh.y >> 16))    + h2f((u16)(ul.y >> 16));
            if (HEAD) {
                pb[p2] += v0 * hbv[nh].x + v1 * hbv[nh].y + v2 * hbv[nh].z + v3 * hbv[nh].w;
                pg[p2] += v0 * hgv[nh].x + v1 * hgv[nh].y + v2 * hgv[nh].z + v3 * hgv[nh].w;
            } else {
                u16 h0 = f2h(v0), h1 = f2h(v1), h2 = f2h(v2), h3 = f2h(v3);
                uint2 oh, ol;
                oh.x = (u32)h0 | ((u32)h1 << 16);
                oh.y = (u32)h2 | ((u32)h3 << 16);
                ol.x = (u32)f2h(v0 - h2f(h0)) | ((u32)f2h(v1 - h2f(h1)) << 16);
                ol.y = (u32)f2h(v2 - h2f(h2)) | ((u32)f2h(v3 - h2f(h3)) << 16);
                *(uint2*)(HHi + gidx) = oh;
                *(uint2*)(HLo + gidx) = ol;
            }
        }
    }

    if (HEAD) {
        #pragma unroll
        for (int p2 = 0; p2 < 8; p2++) {
            float sb = pb[p2], sg = pg[p2];
            #pragma unroll
            for (int off = 1; off < 8; off <<= 1) {
                sb += __shfl_xor(sb, off);
                sg += __shfl_xor(sg, off);
            }
            if ((ln & 7) == 0) {
                int grow = row0 + rbase + cr + p2 * 8;
                atomicAdd(&bSum[grow], sb);
                atomicAdd(&gSum[grow], sg);
            }
        }
    }
}

// ---------------------------------------------------------------------------
// Kernel 4: per-(b,n) SIR recurrence (applies head sigmoids itself).
// ---------------------------------------------------------------------------
__global__ __launch_bounds__(256)
void k_sir(const float* __restrict__ x_state,
           const float* __restrict__ bSum, const float* __restrict__ gSum,
           const float* __restrict__ bb, const float* __restrict__ bg,
           float* __restrict__ out)
{
    const int row = blockIdx.x * 256 + threadIdx.x;   // b*NN + n
    const int bb_ = row / NN;
    const int n   = row % NN;

    const float g = 1.f / (1.f + expf(-(gSum[row] + bg[0])));
    const float b = 1.f / (1.f + expf(-(bSum[row] + bb[0])));
    const float d = expf(-g);

    const float* xs = x_state + ((size_t)bb_ * IN_LEN) * (NN * 3) + (size_t)n * 3;

    float x1_prev = xs[1];
    float Ih_prev = x1_prev / g;
    float acc = 0.f;
    #pragma unroll 4
    for (int t = 1; t <= IN_LEN - 1; ++t) {
        float x1 = xs[(size_t)t * (NN * 3) + 1];
        float Ih = x1 / g;
        float Iin = fmaxf(Ih - Ih_prev + x1_prev, 0.f);
        acc = acc * d + Iin;
        Ih_prev = Ih;
        x1_prev = x1;
    }
    float ITm1 = acc * d;
    float Npop = xs[(size_t)(IN_LEN - 1) * (NN * 3) + 2];
    float RTm1 = Npop - xs[(size_t)(IN_LEN - 2) * (NN * 3) + 0];
    float STm1 = Npop - ITm1 - RTm1;
    float Iin0 = b * STm1 * ITm1 / Npop;
    float S = STm1 - Iin0;
    float I = d * (ITm1 + Iin0);

    float* op = out + ((size_t)bb_ * OUT_LEN) * NN + n;
    #pragma unroll 4
    for (int k = 0; k < OUT_LEN; k++) {
        float Iin = b * S * I / Npop;
        S = S - Iin;
        float Rin = g * I;
        I = d * (I + Iin);
        op[(size_t)k * NN] = Rin;
    }
}

// ---------------------------------------------------------------------------
extern "C" void kernel_launch(void* const* d_in, const int* in_sizes, int n_in,
                              void* d_out, int out_size, void* d_ws, size_t ws_size,
                              hipStream_t stream)
{
    const float* x_node   = (const float*)d_in[0];
    const float* x_state  = (const float*)d_in[1];
    const float* node_emb = (const float*)d_in[2];
    const float* W_ts     = (const float*)d_in[3];
    const float* b_ts     = (const float*)d_in[4];
    const float* enc_W1   = (const float*)d_in[5];
    const float* enc_b1   = (const float*)d_in[6];
    const float* enc_W2   = (const float*)d_in[7];
    const float* enc_b2   = (const float*)d_in[8];
    const float* Wb       = (const float*)d_in[9];
    const float* bb       = (const float*)d_in[10];
    const float* Wg       = (const float*)d_in[11];
    const float* bg       = (const float*)d_in[12];
    float* out = (float*)d_out;

    // Workspace: hhi 64M | hlo 64M | wHi 3M | wLo 3M | bSum | gSum | z (chunked)
    u16* hhi   = (u16*)d_ws;
    u16* hlo   = hhi + (size_t)M_ROWS * H;
    u16* wHi   = hlo + (size_t)M_ROWS * H;          // [6][512][512]
    u16* wLo   = wHi + (size_t)6 * H * H;
    float* bSum = (float*)(wLo + (size_t)6 * H * H);
    float* gSum = bSum + M_ROWS;
    u16* z     = (u16*)(gSum + M_ROWS);

    size_t used  = (size_t)((char*)z - (char*)d_ws);
    size_t avail = (ws_size > used) ? ws_size - used : 0;
    long long chunkLL = (long long)(avail / (H * sizeof(u16))) & ~1023LL;
    int chunk = (chunkLL > M_ROWS) ? M_ROWS : (int)chunkLL;
    if (chunk < 1024) chunk = 1024;
    // (R11 measured: L3 already absorbs the h/z re-reads; row-chunking through
    // layers added dispatch overhead with no fetch reduction. Full-M it is.)

    // zero the head accumulators (d_ws is re-poisoned before every call)
    hipMemsetAsync(bSum, 0, 2 * (size_t)M_ROWS * sizeof(float), stream);

    // weight conversion (redone every call)
    const int nW = N_LAYERS * H * H;   // 786432
    k_split2<<<2 * nW / 256, 256, 0, stream>>>(enc_W1, enc_W2, wHi, wLo, nW);

    // 1. build h (split)
    k_ts<<<dim3(NN / 64, BATCH), 256, 0, stream>>>(x_node, node_emb, W_ts, b_ts, hhi, hlo);

    // 2. encoder layers
    for (int l = 0; l < N_LAYERS; l++) {
        const u16* W1hi = wHi + (size_t)l * H * H;
        const u16* W1lo = wLo + (size_t)l * H * H;
        const u16* W2hi = wHi + (size_t)nW + (size_t)l * H * H;
        const u16* W2lo = wLo + (size_t)nW + (size_t)l * H * H;
        const float* b1 = enc_b1 + (size_t)l * H;
        const float* b2 = enc_b2 + (size_t)l * H;
        for (int r = 0; r < M_ROWS; r += chunk) {
            int rows = (M_ROWS - r < chunk) ? (M_ROWS - r) : chunk;
            u16* hrhi = hhi + (size_t)r * H;
            u16* hrlo = hlo + (size_t)r * H;
            int nblk = (rows / 128) * 4;
            k_gemm1<<<nblk, 256, 0, stream>>>(hrhi, hrlo, W1hi, W1lo, b1, z);
            if (l < N_LAYERS - 1)
                k_gemm2<0><<<nblk, 256, 0, stream>>>(z, W2hi, W2lo, b2, hrhi, hrlo,
                                                     Wb, Wg, bSum + r, gSum + r);
            else
                k_gemm2<1><<<nblk, 256, 0, stream>>>(z, W2hi, W2lo, b2, hrhi, hrlo,
                                                     Wb, Wg, bSum + r, gSum + r);
        }
    }

    // 3. SIR recurrence + output (head sigmoid fused)
    k_sir<<<M_ROWS / 256, 256, 0, stream>>>(x_state, bSum, gSum, bb, bg, out);
}

// Round 8
// 700.299 us; speedup vs baseline: 1.0511x; 1.0444x over previous
//
#include <hip/hip_runtime.h>
#include <hip/hip_bf16.h>
#include <math.h>

// Problem constants
#define BATCH 32
#define IN_LEN 28
#define NN 2048
#define E 256
#define H 512
#define N_LAYERS 3
#define OUT_LEN 28
#define M_ROWS (BATCH * NN)   // 65536

typedef unsigned short u16;
typedef unsigned int   u32;
typedef __attribute__((ext_vector_type(8))) short short8;   // 8 f16 (4 VGPRs)
typedef __attribute__((ext_vector_type(4))) float f32x4;    // MFMA accumulator

// Counted-vmcnt pipeline primitives. Raw barrier (builtin, no compiler
// vmcnt(0) drain) + per-wave counted waits keep prefetch loads in flight
// across barriers.
#define WAITV(N)  asm volatile("s_waitcnt vmcnt(" #N ")" ::: "memory")
#define BARRIER() __builtin_amdgcn_s_barrier()

// ---- fp16 split helpers (RNE casts) ----------------------------------------
__device__ __forceinline__ u16 f2h(float x) {
    union { _Float16 h; u16 u; } v; v.h = (_Float16)x; return v.u;
}
__device__ __forceinline__ float h2f(u16 u) {
    union { _Float16 h; u16 u; } v; v.u = u; return (float)v.h;
}

// async global -> LDS, 16 B per lane. LDS dest = wave-uniform base + lane*16.
__device__ __forceinline__ void gload_lds16(const void* g, void* l) {
    __builtin_amdgcn_global_load_lds(
        (const __attribute__((address_space(1))) void*)g,
        (__attribute__((address_space(3))) void*)l, 16, 0, 0);
}

// ---------------------------------------------------------------------------
// Split BOTH weight tensors into fp16 hi/lo (one launch).
// ---------------------------------------------------------------------------
__global__ __launch_bounds__(256)
void k_split2(const float* __restrict__ w1, const float* __restrict__ w2,
              u16* __restrict__ hi, u16* __restrict__ lo, int nW)
{
    int i = blockIdx.x * 256 + threadIdx.x;
    float v = (i < nW) ? w1[i] : w2[i - nW];
    u16 h = f2h(v);
    hi[i] = h;
    lo[i] = f2h(v - h2f(h));
}

// ---------------------------------------------------------------------------
// Kernel 1: ts = flat @ W_ts^T + b_ts ; h = concat([ts, node_emb]) -> split
// ---------------------------------------------------------------------------
__global__ __launch_bounds__(256)
void k_ts(const float* __restrict__ x_node, const float* __restrict__ node_emb,
          const float* __restrict__ W_ts, const float* __restrict__ b_ts,
          u16* __restrict__ hhi, u16* __restrict__ hlo)
{
    __shared__ float xs[IN_LEN][64];
    const int tid = threadIdx.x;
    const int b   = blockIdx.y;
    const int n0  = blockIdx.x * 64;
    const int c   = tid & 127;        // col pair index
    const int sec = tid >> 7;         // 0: ts, 1: emb (wave-uniform)

    for (int idx = tid; idx < IN_LEN * 64; idx += 256) {
        int l = idx >> 6, i = idx & 63;
        xs[l][i] = x_node[((size_t)b * IN_LEN + l) * NN + n0 + i];
    }

    float w0[IN_LEN], w1[IN_LEN];
    float bias0 = 0.f, bias1 = 0.f;
    if (sec == 0) {
        #pragma unroll
        for (int j = 0; j < IN_LEN; j++) {
            w0[j] = W_ts[(2 * c) * IN_LEN + j];
            w1[j] = W_ts[(2 * c + 1) * IN_LEN + j];
        }
        bias0 = b_ts[2 * c];
        bias1 = b_ts[2 * c + 1];
    }
    __syncthreads();

    for (int i = 0; i < 64; i++) {
        size_t row = (size_t)b * NN + n0 + i;
        u32* oh = (u32*)(hhi + row * H);
        u32* ol = (u32*)(hlo + row * H);
        float v0, v1;
        int oc;
        if (sec == 0) {
            v0 = bias0; v1 = bias1;
            #pragma unroll
            for (int j = 0; j < IN_LEN; j++) {
                float x = xs[j][i];
                v0 += x * w0[j];
                v1 += x * w1[j];
            }
            oc = c;
        } else {
            const float2 ev = *(const float2*)&node_emb[(size_t)(n0 + i) * 256 + 2 * c];
            v0 = ev.x; v1 = ev.y;
            oc = 128 + c;
        }
        u16 h0 = f2h(v0), h1 = f2h(v1);
        oh[oc] = (u32)h0 | ((u32)h1 << 16);
        ol[oc] = (u32)f2h(v0 - h2f(h0)) | ((u32)f2h(v1 - h2f(h1)) << 16);
    }
}

// ---------------------------------------------------------------------------
// Kernel 2a: GEMM1  z = relu(h @ W1^T + b1), h split (3-term), z fp16 SINGLE.
// R8: same 128x128 tile / LDS layout / vmcnt discipline as the measured-best
// R3 kernel, but 512 threads / 8 waves: each wave owns 64x32 (acc 4x2).
// 2 blocks/CU x 8 waves = 16 waves/CU (4/SIMD) — doubles TLP at the barrier
// drains (R7 counters: Occupancy ~20%, both pipes <50% => latency-bound).
// Staging: wave-pair per stream, 4 gloads/stage/wave.
// A-streams (wv0..3): 3 bufs, dist-2, steady vmcnt(4).
// W-streams (wv4..7): 2 bufs, dist-1, vmcnt(0).
// ---------------------------------------------------------------------------
__global__ __launch_bounds__(512)
void k_gemm1(const u16* __restrict__ Ahi, const u16* __restrict__ Alo,
             const u16* __restrict__ Whi, const u16* __restrict__ Wlo,
             const float* __restrict__ bias, u16* __restrict__ Z)
{
    __shared__ __align__(16) u16 smem[40960];   // 80 KB

    const int tid = threadIdx.x;
    const int ln  = tid & 63;
    const int wv  = tid >> 6;       // 0..7

    const int id   = blockIdx.x;
    const int c    = (id >> 3) & 3;
    const int r    = (id & 7) | ((id >> 5) << 3);
    const int row0 = r * 128;
    const int col0 = c * 128;

    const int rbase = (wv & 1) * 64;     // output rows: 2 halves
    const int cbase = (wv >> 1) * 32;    // output cols: 4 quarters

    const int lr = ln >> 2;
    const int lc = ln & 3;

    // staging: stream = wv>>1 (0 Ahi,1 Alo,2 Whi,3 Wlo), q = row-half
    const int strm = wv >> 1;
    const int q    = wv & 1;
    const u16* sgsrc = (strm == 0) ? Ahi : (strm == 1) ? Alo
                     : (strm == 2) ? Whi : Wlo;
    const int sofs = (strm == 0) ? 0 : (strm == 1) ? 12288
                   : (strm == 2) ? 24576 : 32768;
    const int tb   = (strm < 2) ? row0 : col0;

    auto stage = [&](int p, int kt) {
        u16* dstbuf = smem + sofs + p * 4096 + q * 2048;
        #pragma unroll
        for (int i = 0; i < 4; i++) {
            int row = q * 64 + i * 16 + lr;
            int sc  = lc ^ ((row >> 1) & 3);
            gload_lds16(sgsrc + (size_t)(tb + row) * H + kt + sc * 8,
                        dstbuf + i * 512);
        }
    };

    f32x4 acc[4][2];
    #pragma unroll
    for (int m = 0; m < 4; m++)
        #pragma unroll
        for (int n = 0; n < 2; n++) acc[m][n] = (f32x4)(0.f);

    // Prologue: all waves stage tile 0; A-waves also tile 1 (dist-2).
    stage(0, 0);
    if (wv < 4) stage(1, 32);

    const int wl = ln & 15;

    for (int t = 0; t < 16; t++) {
        // A-waves: outstanding {t,t+1} = 8 loads -> vmcnt(4) retires stage(t).
        if (wv < 4) { if (t < 15) { WAITV(4); } else { WAITV(0); } }
        else        { WAITV(0); }
        BARRIER();
        if (wv < 4) { if (t + 2 < 16) stage((t + 2) % 3, (t + 2) * 32); }
        else        { if (t + 1 < 16) stage((t + 1) & 1, (t + 1) * 32); }

        const int pa = t % 3, pw = t & 1;
        const u16* bAh = smem + 0     + pa * 4096;
        const u16* bAl = smem + 12288 + pa * 4096;
        const u16* bWh = smem + 24576 + pw * 4096;
        const u16* bWl = smem + 32768 + pw * 4096;

        short8 ahi[4], alo[4], whi[2], wlo[2];
        #pragma unroll
        for (int m = 0; m < 4; m++) {
            int rr = rbase + m * 16 + wl;
            int cc = ((ln >> 4) ^ ((rr >> 1) & 3)) * 8;
            ahi[m] = *(const short8*)&bAh[rr * 32 + cc];
            alo[m] = *(const short8*)&bAl[rr * 32 + cc];
        }
        #pragma unroll
        for (int n = 0; n < 2; n++) {
            int wr = cbase + n * 16 + wl;
            int cc = ((ln >> 4) ^ ((wr >> 1) & 3)) * 8;
            whi[n] = *(const short8*)&bWh[wr * 32 + cc];
            wlo[n] = *(const short8*)&bWl[wr * 32 + cc];
        }
        #pragma unroll
        for (int m = 0; m < 4; m++)
            #pragma unroll
            for (int n = 0; n < 2; n++) {
                acc[m][n] = __builtin_amdgcn_mfma_f32_16x16x32_f16(ahi[m], whi[n], acc[m][n], 0, 0, 0);
                acc[m][n] = __builtin_amdgcn_mfma_f32_16x16x32_f16(ahi[m], wlo[n], acc[m][n], 0, 0, 0);
                acc[m][n] = __builtin_amdgcn_mfma_f32_16x16x32_f16(alo[m], whi[n], acc[m][n], 0, 0, 0);
            }
    }

    // ---- LDS-bounce epilogue (per-wave-private region) ----
    __syncthreads();                     // staging LDS dead; reuse
    u16* zb = smem + wv * 2048;          // per-wave 64x32 u16 (4 KB)
    float bv[2];
    #pragma unroll
    for (int n = 0; n < 2; n++) bv[n] = bias[col0 + cbase + n * 16 + wl];
    #pragma unroll
    for (int m = 0; m < 4; m++)
        #pragma unroll
        for (int n = 0; n < 2; n++)
            #pragma unroll
            for (int rg = 0; rg < 4; rg++) {
                int row_l = m * 16 + (ln >> 4) * 4 + rg;
                zb[row_l * 32 + n * 16 + wl] =
                    f2h(fmaxf(acc[m][n][rg] + bv[n], 0.f));
            }
    const int cr = ln >> 2;          // 0..15
    const int cq = (ln & 3) * 8;     // u16 col
    #pragma unroll
    for (int p2 = 0; p2 < 4; p2++) {
        int row_l = cr + p2 * 16;
        uint4 v = *(const uint4*)&zb[row_l * 32 + cq];
        *(uint4*)&Z[(size_t)(row0 + rbase + row_l) * H + col0 + cbase + cq] = v;
    }
}

// ---------------------------------------------------------------------------
// Kernel 2b: GEMM2  h += z @ W2^T + b2, z fp16 single (2-term), out split.
// R8: 512 threads / 8 waves, each 64x32 (acc 4x2); same LDS layout and
// prefetch distances as R3. Z-streams (wv0,1): 4 bufs dist-3 vmcnt(8/4/0).
// W-streams (wv2..5): 3 bufs dist-2 vmcnt(4). wv6,7: no staging role.
// T14 batch epilogue prefetch. HEAD=1: fused b/g GEMV, skips h stores.
// ---------------------------------------------------------------------------
template <int HEAD>
__global__ __launch_bounds__(512)
void k_gemm2(const u16* __restrict__ Z,
             const u16* __restrict__ Whi, const u16* __restrict__ Wlo,
             const float* __restrict__ bias,
             u16* HHi, u16* HLo,
             const float* __restrict__ Wb, const float* __restrict__ Wg,
             float* __restrict__ bSum, float* __restrict__ gSum)
{
    __shared__ __align__(16) u16 smem[40960];   // 80 KB

    const int tid = threadIdx.x;
    const int ln  = tid & 63;
    const int wv  = tid >> 6;       // 0..7

    const int id   = blockIdx.x;
    const int c    = (id >> 3) & 3;
    const int r    = (id & 7) | ((id >> 5) << 3);
    const int row0 = r * 128;
    const int col0 = c * 128;

    const int rbase = (wv & 1) * 64;
    const int cbase = (wv >> 1) * 32;

    const int lr = ln >> 2;
    const int lc = ln & 3;

    // LDS layout (u16 idx): Z 4 bufs @0, Whi 3 bufs @16384, Wlo 3 bufs @28672
    const bool zw = (wv < 2);
    const bool ww = (wv >= 2) && (wv < 6);
    const int q = wv & 1;
    const u16* sgsrc = zw ? Z : (wv < 4 ? Whi : Wlo);
    const int sofs = zw ? 0 : (wv < 4 ? 16384 : 28672);
    const int tb   = zw ? row0 : col0;

    auto stage = [&](int p, int kt) {
        u16* dstbuf = smem + sofs + p * 4096 + q * 2048;
        #pragma unroll
        for (int i = 0; i < 4; i++) {
            int row = q * 64 + i * 16 + lr;
            int sc  = lc ^ ((row >> 1) & 3);
            gload_lds16(sgsrc + (size_t)(tb + row) * H + kt + sc * 8,
                        dstbuf + i * 512);
        }
    };

    f32x4 acc[4][2];
    #pragma unroll
    for (int m = 0; m < 4; m++)
        #pragma unroll
        for (int n = 0; n < 2; n++) acc[m][n] = (f32x4)(0.f);

    // Prologue: Z-waves stage 0,1,2 (12 loads); W-waves stage 0,1 (8 loads).
    if (zw)      { stage(0, 0); stage(1, 32); stage(2, 64); }
    else if (ww) { stage(0, 0); stage(1, 32); }

    const int wl = ln & 15;

    for (int t = 0; t < 16; t++) {
        if (zw) {
            // outstanding {t,t+1,t+2} = 12 loads -> vmcnt(8) retires stage(t)
            if      (t < 14) { WAITV(8); }
            else if (t == 14){ WAITV(4); }
            else             { WAITV(0); }
        } else if (ww) {
            // outstanding {t,t+1} = 8 loads -> vmcnt(4) retires stage(t)
            if (t < 15) { WAITV(4); } else { WAITV(0); }
        }
        BARRIER();
        if (zw)      { if (t + 3 < 16) stage((t + 3) & 3, (t + 3) * 32); }
        else if (ww) { if (t + 2 < 16) stage((t + 2) % 3, (t + 2) * 32); }

        const int pz = t & 3, pw3 = t % 3;
        const u16* bZ  = smem + 0     + pz  * 4096;
        const u16* bWh = smem + 16384 + pw3 * 4096;
        const u16* bWl = smem + 28672 + pw3 * 4096;

        short8 az[4], whi[2], wlo[2];
        #pragma unroll
        for (int m = 0; m < 4; m++) {
            int rr = rbase + m * 16 + wl;
            int cc = ((ln >> 4) ^ ((rr >> 1) & 3)) * 8;
            az[m] = *(const short8*)&bZ[rr * 32 + cc];
        }
        #pragma unroll
        for (int n = 0; n < 2; n++) {
            int wr = cbase + n * 16 + wl;
            int cc = ((ln >> 4) ^ ((wr >> 1) & 3)) * 8;
            whi[n] = *(const short8*)&bWh[wr * 32 + cc];
            wlo[n] = *(const short8*)&bWl[wr * 32 + cc];
        }
        #pragma unroll
        for (int m = 0; m < 4; m++)
            #pragma unroll
            for (int n = 0; n < 2; n++) {
                acc[m][n] = __builtin_amdgcn_mfma_f32_16x16x32_f16(az[m], whi[n], acc[m][n], 0, 0, 0);
                acc[m][n] = __builtin_amdgcn_mfma_f32_16x16x32_f16(az[m], wlo[n], acc[m][n], 0, 0, 0);
            }
    }

    // ---- epilogue: batch-prefetch ALL global reads, then LDS-bounce ----
    const int cr  = ln >> 3;           // 0..7
    const int ccl = (ln & 7) * 4;      // u16 col within 32
    const int gc0 = col0 + cbase + ccl;

    uint2  uhv[8], ulv[8];
    float4 bvv = *(const float4*)&bias[gc0];
    float4 hbv, hgv;
    if (HEAD) {
        hbv = *(const float4*)&Wb[gc0];
        hgv = *(const float4*)&Wg[gc0];
    }
    #pragma unroll
    for (int p2 = 0; p2 < 8; p2++) {
        size_t gidx = (size_t)(row0 + rbase + cr + p2 * 8) * H + gc0;
        uhv[p2] = *(const uint2*)(HHi + gidx);
        ulv[p2] = *(const uint2*)(HLo + gidx);
    }

    BARRIER();                                    // staging LDS dead; reuse
    float* fb = (float*)smem + wv * 2048;         // per-wave 64x32 f32 (8 KB)

    float pb[8], pg[8];
    if (HEAD) {
        #pragma unroll
        for (int p2 = 0; p2 < 8; p2++) { pb[p2] = 0.f; pg[p2] = 0.f; }
    }

    #pragma unroll
    for (int m = 0; m < 4; m++)
        #pragma unroll
        for (int j = 0; j < 2; j++)
            #pragma unroll
            for (int rg = 0; rg < 4; rg++) {
                int row_l = m * 16 + (ln >> 4) * 4 + rg;
                fb[row_l * 32 + j * 16 + wl] = acc[m][j][rg];
            }
    #pragma unroll
    for (int p2 = 0; p2 < 8; p2++) {
        int row_l = cr + p2 * 8;
        size_t gidx = (size_t)(row0 + rbase + row_l) * H + gc0;
        uint2 uh = uhv[p2];
        uint2 ul = ulv[p2];
        float4 a = *(const float4*)&fb[row_l * 32 + ccl];
        float v0 = a.x + bvv.x + h2f((u16)(uh.x & 0xFFFF)) + h2f((u16)(ul.x & 0xFFFF));
        float v1 = a.y + bvv.y + h2f((u16)(uh.x >> 16))    + h2f((u16)(ul.x >> 16));
        float v2 = a.z + bvv.z + h2f((u16)(uh.y & 0xFFFF)) + h2f((u16)(ul.y & 0xFFFF));
        float v3 = a.w + bvv.w + h2f((u16)(uh.y >> 16))    + h2f((u16)(ul.y >> 16));
        if (HEAD) {
            pb[p2] += v0 * hbv.x + v1 * hbv.y + v2 * hbv.z + v3 * hbv.w;
            pg[p2] += v0 * hgv.x + v1 * hgv.y + v2 * hgv.z + v3 * hgv.w;
        } else {
            u16 h0 = f2h(v0), h1 = f2h(v1), h2 = f2h(v2), h3 = f2h(v3);
            uint2 oh, ol;
            oh.x = (u32)h0 | ((u32)h1 << 16);
            oh.y = (u32)h2 | ((u32)h3 << 16);
            ol.x = (u32)f2h(v0 - h2f(h0)) | ((u32)f2h(v1 - h2f(h1)) << 16);
            ol.y = (u32)f2h(v2 - h2f(h2)) | ((u32)f2h(v3 - h2f(h3)) << 16);
            *(uint2*)(HHi + gidx) = oh;
            *(uint2*)(HLo + gidx) = ol;
        }
    }

    if (HEAD) {
        #pragma unroll
        for (int p2 = 0; p2 < 8; p2++) {
            float sb = pb[p2], sg = pg[p2];
            #pragma unroll
            for (int off = 1; off < 8; off <<= 1) {
                sb += __shfl_xor(sb, off);
                sg += __shfl_xor(sg, off);
            }
            if ((ln & 7) == 0) {
                int grow = row0 + rbase + cr + p2 * 8;
                atomicAdd(&bSum[grow], sb);
                atomicAdd(&gSum[grow], sg);
            }
        }
    }
}

// ---------------------------------------------------------------------------
// Kernel 4: per-(b,n) SIR recurrence (applies head sigmoids itself).
// ---------------------------------------------------------------------------
__global__ __launch_bounds__(256)
void k_sir(const float* __restrict__ x_state,
           const float* __restrict__ bSum, const float* __restrict__ gSum,
           const float* __restrict__ bb, const float* __restrict__ bg,
           float* __restrict__ out)
{
    const int row = blockIdx.x * 256 + threadIdx.x;   // b*NN + n
    const int bb_ = row / NN;
    const int n   = row % NN;

    const float g = 1.f / (1.f + expf(-(gSum[row] + bg[0])));
    const float b = 1.f / (1.f + expf(-(bSum[row] + bb[0])));
    const float d = expf(-g);

    const float* xs = x_state + ((size_t)bb_ * IN_LEN) * (NN * 3) + (size_t)n * 3;

    float x1_prev = xs[1];
    float Ih_prev = x1_prev / g;
    float acc = 0.f;
    #pragma unroll 4
    for (int t = 1; t <= IN_LEN - 1; ++t) {
        float x1 = xs[(size_t)t * (NN * 3) + 1];
        float Ih = x1 / g;
        float Iin = fmaxf(Ih - Ih_prev + x1_prev, 0.f);
        acc = acc * d + Iin;
        Ih_prev = Ih;
        x1_prev = x1;
    }
    float ITm1 = acc * d;
    float Npop = xs[(size_t)(IN_LEN - 1) * (NN * 3) + 2];
    float RTm1 = Npop - xs[(size_t)(IN_LEN - 2) * (NN * 3) + 0];
    float STm1 = Npop - ITm1 - RTm1;
    float Iin0 = b * STm1 * ITm1 / Npop;
    float S = STm1 - Iin0;
    float I = d * (ITm1 + Iin0);

    float* op = out + ((size_t)bb_ * OUT_LEN) * NN + n;
    #pragma unroll 4
    for (int k = 0; k < OUT_LEN; k++) {
        float Iin = b * S * I / Npop;
        S = S - Iin;
        float Rin = g * I;
        I = d * (I + Iin);
        op[(size_t)k * NN] = Rin;
    }
}

// ---------------------------------------------------------------------------
extern "C" void kernel_launch(void* const* d_in, const int* in_sizes, int n_in,
                              void* d_out, int out_size, void* d_ws, size_t ws_size,
                              hipStream_t stream)
{
    const float* x_node   = (const float*)d_in[0];
    const float* x_state  = (const float*)d_in[1];
    const float* node_emb = (const float*)d_in[2];
    const float* W_ts     = (const float*)d_in[3];
    const float* b_ts     = (const float*)d_in[4];
    const float* enc_W1   = (const float*)d_in[5];
    const float* enc_b1   = (const float*)d_in[6];
    const float* enc_W2   = (const float*)d_in[7];
    const float* enc_b2   = (const float*)d_in[8];
    const float* Wb       = (const float*)d_in[9];
    const float* bb       = (const float*)d_in[10];
    const float* Wg       = (const float*)d_in[11];
    const float* bg       = (const float*)d_in[12];
    float* out = (float*)d_out;

    // Workspace: hhi 64M | hlo 64M | wHi 3M | wLo 3M | bSum | gSum | z (chunked)
    u16* hhi   = (u16*)d_ws;
    u16* hlo   = hhi + (size_t)M_ROWS * H;
    u16* wHi   = hlo + (size_t)M_ROWS * H;          // [6][512][512]
    u16* wLo   = wHi + (size_t)6 * H * H;
    float* bSum = (float*)(wLo + (size_t)6 * H * H);
    float* gSum = bSum + M_ROWS;
    u16* z     = (u16*)(gSum + M_ROWS);

    size_t used  = (size_t)((char*)z - (char*)d_ws);
    size_t avail = (ws_size > used) ? ws_size - used : 0;
    long long chunkLL = (long long)(avail / (H * sizeof(u16))) & ~1023LL;
    int chunk = (chunkLL > M_ROWS) ? M_ROWS : (int)chunkLL;
    if (chunk < 1024) chunk = 1024;
    // (R11 measured: L3 already absorbs the h/z re-reads; row-chunking through
    // layers added dispatch overhead with no fetch reduction. Full-M it is.)

    // zero the head accumulators (d_ws is re-poisoned before every call)
    hipMemsetAsync(bSum, 0, 2 * (size_t)M_ROWS * sizeof(float), stream);

    // weight conversion (redone every call)
    const int nW = N_LAYERS * H * H;   // 786432
    k_split2<<<2 * nW / 256, 256, 0, stream>>>(enc_W1, enc_W2, wHi, wLo, nW);

    // 1. build h (split)
    k_ts<<<dim3(NN / 64, BATCH), 256, 0, stream>>>(x_node, node_emb, W_ts, b_ts, hhi, hlo);

    // 2. encoder layers
    for (int l = 0; l < N_LAYERS; l++) {
        const u16* W1hi = wHi + (size_t)l * H * H;
        const u16* W1lo = wLo + (size_t)l * H * H;
        const u16* W2hi = wHi + (size_t)nW + (size_t)l * H * H;
        const u16* W2lo = wLo + (size_t)nW + (size_t)l * H * H;
        const float* b1 = enc_b1 + (size_t)l * H;
        const float* b2 = enc_b2 + (size_t)l * H;
        for (int r = 0; r < M_ROWS; r += chunk) {
            int rows = (M_ROWS - r < chunk) ? (M_ROWS - r) : chunk;
            u16* hrhi = hhi + (size_t)r * H;
            u16* hrlo = hlo + (size_t)r * H;
            int nblk = (rows / 128) * 4;
            k_gemm1<<<nblk, 512, 0, stream>>>(hrhi, hrlo, W1hi, W1lo, b1, z);
            if (l < N_LAYERS - 1)
                k_gemm2<0><<<nblk, 512, 0, stream>>>(z, W2hi, W2lo, b2, hrhi, hrlo,
                                                     Wb, Wg, bSum + r, gSum + r);
            else
                k_gemm2<1><<<nblk, 512, 0, stream>>>(z, W2hi, W2lo, b2, hrhi, hrlo,
                                                     Wb, Wg, bSum + r, gSum + r);
        }
    }

    // 3. SIR recurrence + output (head sigmoid fused)
    k_sir<<<M_ROWS / 256, 256, 0, stream>>>(x_state, bSum, gSum, bb, bg, out);
}